// Round 10
// baseline (503.044 us; speedup 1.0000x reference)
//
#include <hip/hip_runtime.h>

// ToDenseBEVConvolution R10 — MEASUREMENT ROUND. Byte-identical to R9 except
// bev_dense_row is launched 3x (idempotent: overwrites identical data).
// Purpose: D = (Total_R10 - Total_R9)/2 measures the dense pass exactly,
// since rocprof top-5 is saturated by the harness's five 1-GiB poison fills
// and our kernels are invisible. R8 calibrated dispatch gaps at ~3us, so the
// extra 2 launches cost ~6us + 2D.

#define CIN    64
#define COUT   128
#define BEVH   512
#define BEVW   512
#define HW     (BEVH * BEVW)     // 2^18
#define NBINS  16
#define PTS_PER_WAVE  8
#define PTS_PER_BLOCK 32

// ---------------------------------------------------------------- K1: bucket
__global__ __launch_bounds__(256) void bev_sort(
    const int* __restrict__ coords,   // [N,4]
    const int* __restrict__ stride_p,
    int*       __restrict__ gcnt,     // [16] init 0
    int*       __restrict__ sorted,   // [16*N]
    int n)
{
    __shared__ int hist[NBINS];
    __shared__ int base[NBINS];
    const int tid = threadIdx.x;
    if (tid < NBINS) hist[tid] = 0;
    __syncthreads();

    const int i = blockIdx.x * 256 + tid;
    int k = 0, rank = 0;
    if (i < n) {
        k = coords[i * 4 + 1] / stride_p[0];
        rank = atomicAdd(&hist[k], 1);        // LDS atomic: block-local rank
    }
    __syncthreads();
    if (tid < NBINS)
        base[tid] = hist[tid] ? atomicAdd(&gcnt[tid], hist[tid]) : 0;
    __syncthreads();
    if (i < n)
        sorted[k * n + base[k] + rank] = i;
}

// ------------------------------------------------------- K2: per-point matmul
__global__ __launch_bounds__(256) void bev_point(
    const int*   __restrict__ coords,
    const float* __restrict__ feats,    // [N,64]
    const float* __restrict__ kern,     // [16,64,128]
    const int*   __restrict__ stride_p,
    const int*   __restrict__ gcnt,     // [16]
    const int*   __restrict__ sorted,   // [16*N]
    float*       __restrict__ f,        // [N,128]
    int*         __restrict__ head,     // [ncells] init -1
    int*         __restrict__ nxt,      // [N]
    unsigned int* __restrict__ bm,      // [ncells/32] init 0
    int n, int chunks_per_bin)
{
    __shared__ float lk[CIN * COUT];    // 32 KB: kern[bin]

    const int bin   = blockIdx.x / chunks_per_bin;
    const int chunk = blockIdx.x % chunks_per_bin;
    const int cnt   = gcnt[bin];
    const int r0blk = chunk * PTS_PER_BLOCK;
    if (r0blk >= cnt) return;                 // uniform across block, pre-barrier: ok

    // stage kern[bin] -> LDS (256 thr x 8 float4)
    {
        const float4* src = (const float4*)(kern + (size_t)bin * CIN * COUT);
        float4* dst = (float4*)lk;
#pragma unroll
        for (int j = 0; j < 8; ++j)
            dst[j * 256 + threadIdx.x] = src[j * 256 + threadIdx.x];
    }
    __syncthreads();

    const int wave = threadIdx.x >> 6;
    const int lane = threadIdx.x & 63;
    const int r0 = r0blk + wave * PTS_PER_WAVE;
    const int navail = cnt - r0;
    if (navail <= 0) return;                  // no barrier after this point
    const int np = navail < PTS_PER_WAVE ? navail : PTS_PER_WAVE;

    int pts[PTS_PER_WAVE];
#pragma unroll
    for (int p = 0; p < PTS_PER_WAVE; ++p) {
        const int rr = (p < np) ? (r0 + p) : r0;   // pad tail with p0 (discarded)
        pts[p] = __builtin_amdgcn_readfirstlane(sorted[bin * n + rr]);
    }

    float ax[PTS_PER_WAVE], ay[PTS_PER_WAVE];
#pragma unroll
    for (int p = 0; p < PTS_PER_WAVE; ++p) { ax[p] = 0.f; ay[p] = 0.f; }

#pragma unroll
    for (int c = 0; c < CIN; ++c) {
        const float2 kv = *(const float2*)&lk[c * COUT + 2 * lane];
#pragma unroll
        for (int p = 0; p < PTS_PER_WAVE; ++p) {
            const float fv = feats[(size_t)pts[p] * CIN + c];  // wave-uniform -> s_load
            ax[p] = fmaf(fv, kv.x, ax[p]);
            ay[p] = fmaf(fv, kv.y, ay[p]);
        }
    }

#pragma unroll
    for (int p = 0; p < PTS_PER_WAVE; ++p) {
        if (p < np)
            *(float2*)(f + (size_t)pts[p] * COUT + 2 * lane) = make_float2(ax[p], ay[p]);
    }

    if (lane == 0) {
        const int stride = stride_p[0];
        for (int p = 0; p < np; ++p) {
            const int pt = pts[p];
            const int cx = coords[pt * 4 + 0];
            const int cz = coords[pt * 4 + 2];
            const int cb = coords[pt * 4 + 3];
            const int cell = (cb << 18) + ((cx / stride) << 9) + (cz / stride);
            const int old = atomicExch(&head[cell], pt);       // spread: cheap
            nxt[pt] = old;
            atomicOr(&bm[cell >> 5], 1u << (cell & 31));       // spread: cheap
        }
    }
}

// --------------------------------------- K3: word-level popcount prefix scan
__global__ __launch_bounds__(256) void bev_scan(
    const unsigned int* __restrict__ bm,        // [nwords]
    int*                __restrict__ wordbase,  // [nwords] exclusive prefix
    int nwords)
{
    __shared__ int part[256];
    const int tid = threadIdx.x;
    const int per = (nwords + 255) / 256;       // 64 for B=2
    const int w0  = tid * per;

    int s = 0;
    for (int i = 0; i < per; ++i) {
        const int w = w0 + i;
        if (w < nwords) s += __popc(bm[w]);
    }
    part[tid] = s;
    __syncthreads();
    for (int d = 1; d < 256; d <<= 1) {         // Hillis-Steele inclusive scan
        const int v = (tid >= d) ? part[tid - d] : 0;
        __syncthreads();
        part[tid] += v;
        __syncthreads();
    }
    int base = (tid == 0) ? 0 : part[tid - 1];  // exclusive
    for (int i = 0; i < per; ++i) {
        const int w = w0 + i;
        if (w < nwords) { wordbase[w] = base; base += __popc(bm[w]); }
    }
}

// ----------------------------- K4: owner combines collisions -> compacted g
__global__ __launch_bounds__(256) void bev_accum(
    const int*          __restrict__ coords,
    const int*          __restrict__ stride_p,
    const float*        __restrict__ f,         // [N,128]
    const int*          __restrict__ head,
    const int*          __restrict__ nxt,
    const unsigned int* __restrict__ bm,
    const int*          __restrict__ wordbase,
    float*              __restrict__ g,         // [nocc,128] compacted
    int n)
{
    const int wave = threadIdx.x >> 6;
    const int lane = threadIdx.x & 63;
    int pt = blockIdx.x * 4 + wave;
    if (pt >= n) return;
    pt = __builtin_amdgcn_readfirstlane(pt);

    const int stride = stride_p[0];
    const int cx = coords[pt * 4 + 0];
    const int cz = coords[pt * 4 + 2];
    const int cb = coords[pt * 4 + 3];
    const int cell = (cb << 18) + ((cx / stride) << 9) + (cz / stride);

    // exactly one point per occupied cell is the list head: that wave owns it
    if (__builtin_amdgcn_readfirstlane(head[cell]) != pt) return;

    float sx = 0.f, sy = 0.f;
    int p = pt;
    while (p >= 0) {                            // wave-uniform walk, avg len ~1.04
        const float2 v = *(const float2*)(f + (size_t)p * COUT + 2 * lane);
        sx += v.x; sy += v.y;
        p = __builtin_amdgcn_readfirstlane(nxt[p]);
    }

    const unsigned int word = bm[cell >> 5];
    const int bit = cell & 31;
    const int rank = wordbase[cell >> 5] + __popc(word & ((1u << bit) - 1u));

    *(float2*)(g + (size_t)rank * COUT + 2 * lane) = make_float2(sx, sy);  // 512B/cell
}

// ------------------------- K5: wave-per-row dense output (plain stores)
__global__ __launch_bounds__(256) void bev_dense_row(
    const float*        __restrict__ g,         // [nocc,128]
    const unsigned int* __restrict__ bm,
    const int*          __restrict__ wordbase,
    float*              __restrict__ out,       // [B,128,512,512]
    int nrows)                                  // B*COUT*BEVH
{
    const int wave = threadIdx.x >> 6;
    const int lane = threadIdx.x & 63;
    const int row = blockIdx.x * 4 + wave;      // row = ((b*128+o)*512)+x
    if (row >= nrows) return;

    const int x = row & 511;
    const int o = (row >> 9) & 127;             // wave-uniform
    const int b = row >> 16;                    // wave-uniform
    const int wbase = ((b << 18) + (x << 9)) >> 5;   // 16 bm words, one 64B line
    float* const orow = out + (size_t)row * 512;

#pragma unroll
    for (int h = 0; h < 2; ++h) {
        const int z    = h * 256 + lane * 4;    // lane covers 4 consecutive z
        const int widx = wbase + (z >> 5);      // 8 consecutive words per half
        const unsigned int word = bm[widx];
        const int bit = z & 31;
        const unsigned int nib = (word >> bit) & 0xFu;

        float4 v = make_float4(0.f, 0.f, 0.f, 0.f);
        if (nib) {                              // row's ranks are consecutive ->
            int r = wordbase[widx] + __popc(word & ((1u << bit) - 1u));
            float vv[4];
#pragma unroll
            for (int j = 0; j < 4; ++j) {       // contiguous g window, L2-hot
                vv[j] = 0.f;
                if (nib & (1u << j)) { vv[j] = g[(size_t)r * COUT + o]; ++r; }
            }
            v = make_float4(vv[0], vv[1], vv[2], vv[3]);
        }
        *(float4*)(orow + z) = v;               // coalesced 1KB/wave plain store
    }
}

// ------------------------------------------------------------------- launch
extern "C" void kernel_launch(void* const* d_in, const int* in_sizes, int n_in,
                              void* d_out, int out_size, void* d_ws, size_t ws_size,
                              hipStream_t stream) {
    const int*   coords   = (const int*)d_in[0];
    const float* feats    = (const float*)d_in[1];
    const float* kern     = (const float*)d_in[2];
    const int*   stride_p = (const int*)d_in[3];
    float* out = (float*)d_out;

    const int n      = in_sizes[0] / 4;      // coords is [N,4]
    const int ncells = out_size / COUT;      // B*H*W = 524288
    const int nwords = ncells / 32;          // 16384

    // Workspace: f | g | sorted | head | nxt | wordbase | bm | gcnt
    size_t off = 0;
    float* f = (float*)((char*)d_ws + off);          off += (size_t)n * COUT * sizeof(float);
    float* g = (float*)((char*)d_ws + off);          off += (size_t)n * COUT * sizeof(float);
    int* sorted = (int*)((char*)d_ws + off);         off += (size_t)NBINS * n * sizeof(int);
    int* head = (int*)((char*)d_ws + off);           off += (size_t)ncells * sizeof(int);
    int* nxt  = (int*)((char*)d_ws + off);           off += (size_t)n * sizeof(int);
    int* wordbase = (int*)((char*)d_ws + off);       off += (size_t)nwords * sizeof(int);
    unsigned int* bm = (unsigned int*)((char*)d_ws + off); off += (size_t)nwords * sizeof(unsigned int);
    int* gcnt = (int*)((char*)d_ws + off);           off += NBINS * sizeof(int);

    // ws re-poisoned to 0xAA before every timed launch -> re-init.
    (void)hipMemsetAsync(head, 0xFF, (size_t)ncells * sizeof(int), stream);     // -1
    (void)hipMemsetAsync(bm, 0,
                         (size_t)nwords * sizeof(unsigned int) + NBINS * sizeof(int),
                         stream);                                               // bm + gcnt

    bev_sort<<<(n + 255) / 256, 256, 0, stream>>>(coords, stride_p, gcnt, sorted, n);

    const int chunks_per_bin = (n + PTS_PER_BLOCK - 1) / PTS_PER_BLOCK;
    bev_point<<<NBINS * chunks_per_bin, 256, 0, stream>>>(
        coords, feats, kern, stride_p, gcnt, sorted, f, head, nxt, bm,
        n, chunks_per_bin);

    bev_scan<<<1, 256, 0, stream>>>(bm, wordbase, nwords);

    bev_accum<<<(n + 3) / 4, 256, 0, stream>>>(coords, stride_p, f, head, nxt,
                                               bm, wordbase, g, n);

    const int nrows = out_size / 512;        // B*COUT*BEVH = 131072
    // MEASUREMENT: 3x idempotent launches. D = (Total_R10 - Total_R9) / 2.
    bev_dense_row<<<nrows / 4, 256, 0, stream>>>(g, bm, wordbase, out, nrows);
    bev_dense_row<<<nrows / 4, 256, 0, stream>>>(g, bm, wordbase, out, nrows);
    bev_dense_row<<<nrows / 4, 256, 0, stream>>>(g, bm, wordbase, out, nrows);
}

// Round 11
// 350.510 us; speedup vs baseline: 1.4352x; 1.4352x over previous
//
#include <hip/hip_runtime.h>

// ToDenseBEVConvolution R11 — 5 dispatches (R10 found ~12us/dispatch-boundary;
// dense already at fill-rate 44-53us; R9's 7 dispatches paid ~84us in gaps):
//  D1 memset:   head+gcnt zeroed in ONE call (head uses pt+1 encoding, 0=empty).
//  D2 bev_sort: bucket point indices by k-bin (unchanged).
//  D3 bev_point: binned matmul, kern[k] in LDS; f[N,128]; head=pt+1 (atomicExch),
//               nxt[pt]=old (0 = end). No bm.
//  D4 bev_accum: owner (head[cell]==pt+1) with a real collision chain
//               (nxt!=0) sums chain IN-PLACE into its own f row. Chains are
//               disjoint -> no cross-owner hazard. ~96% of cells are
//               singletons -> skip; only ~1.4k waves do work.
//  D5 bev_dense_row: wave per 2KB output row; lane loads head[z..z+3] as ONE
//               coalesced int4 (head row = 2KB contiguous per (b,x)); occupied
//               -> one scattered f load (2-deep chain, level-1 coalesced);
//               1KB coalesced float4 stores. No scan/bm/wordbase.

#define CIN    64
#define COUT   128
#define BEVH   512
#define BEVW   512
#define HW     (BEVH * BEVW)     // 2^18
#define NBINS  16
#define PTS_PER_WAVE  8
#define PTS_PER_BLOCK 32

// ---------------------------------------------------------------- D2: bucket
__global__ __launch_bounds__(256) void bev_sort(
    const int* __restrict__ coords,   // [N,4]
    const int* __restrict__ stride_p,
    int*       __restrict__ gcnt,     // [16] init 0
    int*       __restrict__ sorted,   // [16*N]
    int n)
{
    __shared__ int hist[NBINS];
    __shared__ int base[NBINS];
    const int tid = threadIdx.x;
    if (tid < NBINS) hist[tid] = 0;
    __syncthreads();

    const int i = blockIdx.x * 256 + tid;
    int k = 0, rank = 0;
    if (i < n) {
        k = coords[i * 4 + 1] / stride_p[0];
        rank = atomicAdd(&hist[k], 1);        // LDS atomic: block-local rank
    }
    __syncthreads();
    if (tid < NBINS)
        base[tid] = hist[tid] ? atomicAdd(&gcnt[tid], hist[tid]) : 0;
    __syncthreads();
    if (i < n)
        sorted[k * n + base[k] + rank] = i;
}

// ------------------------------------------------------- D3: per-point matmul
__global__ __launch_bounds__(256) void bev_point(
    const int*   __restrict__ coords,
    const float* __restrict__ feats,    // [N,64]
    const float* __restrict__ kern,     // [16,64,128]
    const int*   __restrict__ stride_p,
    const int*   __restrict__ gcnt,     // [16]
    const int*   __restrict__ sorted,   // [16*N]
    float*       __restrict__ f,        // [N,128]
    int*         __restrict__ head,     // [ncells] init 0; stores pt+1
    int*         __restrict__ nxt,      // [N]; 0 = end-of-chain
    int n, int chunks_per_bin)
{
    __shared__ float lk[CIN * COUT];    // 32 KB: kern[bin]

    const int bin   = blockIdx.x / chunks_per_bin;
    const int chunk = blockIdx.x % chunks_per_bin;
    const int cnt   = gcnt[bin];
    const int r0blk = chunk * PTS_PER_BLOCK;
    if (r0blk >= cnt) return;                 // uniform across block, pre-barrier: ok

    // stage kern[bin] -> LDS (256 thr x 8 float4)
    {
        const float4* src = (const float4*)(kern + (size_t)bin * CIN * COUT);
        float4* dst = (float4*)lk;
#pragma unroll
        for (int j = 0; j < 8; ++j)
            dst[j * 256 + threadIdx.x] = src[j * 256 + threadIdx.x];
    }
    __syncthreads();

    const int wave = threadIdx.x >> 6;
    const int lane = threadIdx.x & 63;
    const int r0 = r0blk + wave * PTS_PER_WAVE;
    const int navail = cnt - r0;
    if (navail <= 0) return;                  // no barrier after this point
    const int np = navail < PTS_PER_WAVE ? navail : PTS_PER_WAVE;

    int pts[PTS_PER_WAVE];
#pragma unroll
    for (int p = 0; p < PTS_PER_WAVE; ++p) {
        const int rr = (p < np) ? (r0 + p) : r0;   // pad tail with p0 (discarded)
        pts[p] = __builtin_amdgcn_readfirstlane(sorted[bin * n + rr]);
    }

    float ax[PTS_PER_WAVE], ay[PTS_PER_WAVE];
#pragma unroll
    for (int p = 0; p < PTS_PER_WAVE; ++p) { ax[p] = 0.f; ay[p] = 0.f; }

#pragma unroll
    for (int c = 0; c < CIN; ++c) {
        const float2 kv = *(const float2*)&lk[c * COUT + 2 * lane];
#pragma unroll
        for (int p = 0; p < PTS_PER_WAVE; ++p) {
            const float fv = feats[(size_t)pts[p] * CIN + c];  // wave-uniform -> s_load
            ax[p] = fmaf(fv, kv.x, ax[p]);
            ay[p] = fmaf(fv, kv.y, ay[p]);
        }
    }

#pragma unroll
    for (int p = 0; p < PTS_PER_WAVE; ++p) {
        if (p < np)
            *(float2*)(f + (size_t)pts[p] * COUT + 2 * lane) = make_float2(ax[p], ay[p]);
    }

    if (lane == 0) {
        const int stride = stride_p[0];
        for (int p = 0; p < np; ++p) {
            const int pt = pts[p];
            const int cx = coords[pt * 4 + 0];
            const int cz = coords[pt * 4 + 2];
            const int cb = coords[pt * 4 + 3];
            const int cell = (cb << 18) + ((cx / stride) << 9) + (cz / stride);
            const int old = atomicExch(&head[cell], pt + 1);   // spread: cheap
            nxt[pt] = old;                                     // 0 = end
        }
    }
}

// ----------------- D4: owner folds collision chain in-place into its f row
__global__ __launch_bounds__(256) void bev_accum(
    const int* __restrict__ coords,
    const int* __restrict__ stride_p,
    float*     __restrict__ f,          // [N,128] (in-place)
    const int* __restrict__ head,
    const int* __restrict__ nxt,
    int n)
{
    const int wave = threadIdx.x >> 6;
    const int lane = threadIdx.x & 63;
    int pt = blockIdx.x * 4 + wave;
    if (pt >= n) return;
    pt = __builtin_amdgcn_readfirstlane(pt);

    const int nx0 = __builtin_amdgcn_readfirstlane(nxt[pt]);
    if (nx0 == 0) return;                       // singleton or tail: nothing to fold

    const int stride = stride_p[0];
    const int cx = coords[pt * 4 + 0];
    const int cz = coords[pt * 4 + 2];
    const int cb = coords[pt * 4 + 3];
    const int cell = (cb << 18) + ((cx / stride) << 9) + (cz / stride);
    if (__builtin_amdgcn_readfirstlane(head[cell]) != pt + 1) return;  // owner only

    float2 acc = *(const float2*)(f + (size_t)pt * COUT + 2 * lane);
    int p = nx0;
    while (p) {                                 // disjoint chains: no hazards
        const float2 v = *(const float2*)(f + (size_t)(p - 1) * COUT + 2 * lane);
        acc.x += v.x; acc.y += v.y;
        p = __builtin_amdgcn_readfirstlane(nxt[p - 1]);
    }
    *(float2*)(f + (size_t)pt * COUT + 2 * lane) = acc;
}

// ------------------- D5: wave-per-row dense output (int4 head, plain stores)
__global__ __launch_bounds__(256) void bev_dense_row(
    const float* __restrict__ f,        // [N,128] (owner rows hold cell sums)
    const int*   __restrict__ head,     // [ncells], pt+1 or 0
    float*       __restrict__ out,      // [B,128,512,512]
    int nrows)                          // B*COUT*BEVH
{
    const int wave = threadIdx.x >> 6;
    const int lane = threadIdx.x & 63;
    const int row = blockIdx.x * 4 + wave;      // row = (b<<16)|(o<<9)|x
    if (row >= nrows) return;

    const int x = row & 511;
    const int o = (row >> 9) & 127;             // wave-uniform
    const int b = row >> 16;                    // wave-uniform
    const int* hrow = head + (b << 18) + (x << 9);   // 2KB contiguous head row
    float* const orow = out + (size_t)row * 512;

#pragma unroll
    for (int h = 0; h < 2; ++h) {
        const int z = h * 256 + lane * 4;
        const int4 h4 = *(const int4*)(hrow + z);    // coalesced 1KB/wave
        float4 v = make_float4(0.f, 0.f, 0.f, 0.f);
        if (h4.x) v.x = f[(size_t)(h4.x - 1) * COUT + o];   // 2-deep chain,
        if (h4.y) v.y = f[(size_t)(h4.y - 1) * COUT + o];   // one scattered
        if (h4.z) v.z = f[(size_t)(h4.z - 1) * COUT + o];   // load level
        if (h4.w) v.w = f[(size_t)(h4.w - 1) * COUT + o];
        *(float4*)(orow + z) = v;                    // coalesced 1KB/wave store
    }
}

// ------------------------------------------------------------------- launch
extern "C" void kernel_launch(void* const* d_in, const int* in_sizes, int n_in,
                              void* d_out, int out_size, void* d_ws, size_t ws_size,
                              hipStream_t stream) {
    const int*   coords   = (const int*)d_in[0];
    const float* feats    = (const float*)d_in[1];
    const float* kern     = (const float*)d_in[2];
    const int*   stride_p = (const int*)d_in[3];
    float* out = (float*)d_out;

    const int n      = in_sizes[0] / 4;      // coords is [N,4]
    const int ncells = out_size / COUT;      // B*H*W = 524288

    // Workspace: f | head | gcnt | nxt | sorted   (head+gcnt contiguous -> 1 memset)
    size_t off = 0;
    float* f = (float*)((char*)d_ws + off);          off += (size_t)n * COUT * sizeof(float);
    int* head = (int*)((char*)d_ws + off);           off += (size_t)ncells * sizeof(int);
    int* gcnt = (int*)((char*)d_ws + off);           off += NBINS * sizeof(int);
    int* nxt  = (int*)((char*)d_ws + off);           off += (size_t)n * sizeof(int);
    int* sorted = (int*)((char*)d_ws + off);         off += (size_t)NBINS * n * sizeof(int);

    // D1: ws re-poisoned to 0xAA before every timed launch -> one zeroing memset
    (void)hipMemsetAsync(head, 0,
                         (size_t)ncells * sizeof(int) + NBINS * sizeof(int), stream);

    // D2
    bev_sort<<<(n + 255) / 256, 256, 0, stream>>>(coords, stride_p, gcnt, sorted, n);

    // D3
    const int chunks_per_bin = (n + PTS_PER_BLOCK - 1) / PTS_PER_BLOCK;
    bev_point<<<NBINS * chunks_per_bin, 256, 0, stream>>>(
        coords, feats, kern, stride_p, gcnt, sorted, f, head, nxt,
        n, chunks_per_bin);

    // D4
    bev_accum<<<(n + 3) / 4, 256, 0, stream>>>(coords, stride_p, f, head, nxt, n);

    // D5
    const int nrows = out_size / 512;        // B*COUT*BEVH = 131072
    bev_dense_row<<<nrows / 4, 256, 0, stream>>>(f, head, out, nrows);
}